// Round 1
// baseline (168.509 us; speedup 1.0000x reference)
//
#include <hip/hip_runtime.h>

// HierarchicalSoftmax: out[b] = prod_l sigmoid(+/- (W[node_l]·emb[b] + bias[node_l]))
//
// R2 restructure vs R1: levels of a path are INDEPENDENT (product is associative),
// so parallelize across them instead of walking them serially on one wave.
//  - One block (4 waves) per sample. Wave w owns levels {w, w+4, w+8, ...}
//    (stride-4 interleave -> balanced across waves).
//  - Within a wave, four 16-lane groups each compute a DIFFERENT level
//    concurrently: 32 floats/lane (8 x float4), reduce = 4 cross-lane ops
//    for 4 levels (vs 6 ops per single level in R1).
//  - Round-1 (levels >= 16+w) node indices + W loads issued BEFORE round-0
//    compute: deep paths cost ~1 memory round-trip, not ~4.4.
//  - Wave products combined via 2 shfl_xor multiplies; waves via 16B LDS.

#define HS_D 512
#define F4PL 8   // float4 per lane: 512 floats / 4 / 16 lanes

__device__ __forceinline__ float fast_sigmoid(float s) {
    // 1/(1+e^-s); v_rcp_f32 rel err ~1e-6, far under the 2%-of-max threshold
    return __builtin_amdgcn_rcpf(1.0f + __expf(-s));
}

__device__ __forceinline__ float dot32(const float4* __restrict__ e,
                                       const float4* __restrict__ a) {
    float p = e[0].x * a[0].x;
    #pragma unroll
    for (int k = 0; k < F4PL; ++k) {
        if (k) p = fmaf(e[k].x, a[k].x, p);
        p = fmaf(e[k].y, a[k].y, p);
        p = fmaf(e[k].z, a[k].z, p);
        p = fmaf(e[k].w, a[k].w, p);
    }
    return p;
}

__global__ __launch_bounds__(256) void hs_kernel(
    const float* __restrict__ emb,     // [B, 512]
    const float* __restrict__ W,       // [V-1, 512]
    const float* __restrict__ bias,    // [V-1]
    const int*   __restrict__ target,  // [B]
    const int*   __restrict__ nodes,   // [V, L]
    const int*   __restrict__ dirs,    // [V, L]
    float*       __restrict__ out,     // [B]
    int B, int L)
{
    const int b    = blockIdx.x;           // one sample per block
    const int wv   = threadIdx.x >> 6;     // wave 0..3
    const int lane = threadIdx.x & 63;
    const int g    = lane >> 4;            // 16-lane group 0..3
    const int gl   = lane & 15;

    __shared__ float wprod[4];

    const int t = __builtin_amdgcn_readfirstlane(target[b]);

    // Lane-parallel preload of the whole path's metadata (L ~ 27 < 64).
    int nval = 0, dval = 0;
    if (lane < L) {
        nval = nodes[(size_t)t * L + lane];
        dval = dirs [(size_t)t * L + lane];
    }
    // First node==0 along the row is the root (= last real step). 1-based pos.
    const unsigned long long rootmask = __ballot(lane < L && nval == 0);
    const int plen = __ffsll((long long)rootmask);
    const unsigned long long dirmask = __ballot(dval != 0);

    // Embedding chunk for this lane: float4 indices gl + 16k (same for all groups).
    const float4* e4 = (const float4*)(emb + (size_t)b * HS_D);
    float4 ek[F4PL];
    #pragma unroll
    for (int k = 0; k < F4PL; ++k) ek[k] = e4[gl + 16 * k];

    // This group's levels: l0 = wv + 4g (round 0), l1 = l0 + 16 (round 1).
    const int l0 = wv + 4 * g;             // 0..15
    const int l1 = l0 + 16;                // 16..31
    const int n0 = __shfl(nval, l0, 64);   // full-exec broadcasts
    const int n1 = __shfl(nval, l1, 64);
    const bool act0 = (l0 < plen);
    const bool act1 = (l1 < plen);

    float lprod = 1.0f;

    // Issue round-1 loads FIRST (prefetch for deep paths), group-uniform branch.
    float4 a1[F4PL];
    if (act1) {
        const float4* w4 = (const float4*)(W + (size_t)n1 * HS_D);
        #pragma unroll
        for (int k = 0; k < F4PL; ++k) a1[k] = w4[gl + 16 * k];
    }

    // Round 0: load + dot + 16-lane reduce.
    if (act0) {
        const float4* w4 = (const float4*)(W + (size_t)n0 * HS_D);
        float4 a0[F4PL];
        #pragma unroll
        for (int k = 0; k < F4PL; ++k) a0[k] = w4[gl + 16 * k];
        const float bi = bias[n0];
        float p = dot32(ek, a0);
        #pragma unroll
        for (int m = 8; m >= 1; m >>= 1) p += __shfl_xor(p, m, 64);
        float s = p + bi;
        s = ((dirmask >> l0) & 1ull) ? s : -s;
        lprod = fast_sigmoid(s);
    }

    // Round 1: data already (mostly) in flight.
    if (act1) {
        const float bi = bias[n1];
        float p = dot32(ek, a1);
        #pragma unroll
        for (int m = 8; m >= 1; m >>= 1) p += __shfl_xor(p, m, 64);
        float s = p + bi;
        s = ((dirmask >> l1) & 1ull) ? s : -s;
        lprod *= fast_sigmoid(s);
    }

    // Generic fallback for L > 32 (never taken at L~27, kept for robustness).
    for (int base = wv + 32; base < plen; base += 16) {   // wave-uniform
        const int l  = base + 4 * g;
        const int ls = (l < 64) ? l : 0;
        const int n  = __shfl(nval, ls, 64);
        if (l < plen) {
            const float4* w4 = (const float4*)(W + (size_t)n * HS_D);
            float4 a[F4PL];
            #pragma unroll
            for (int k = 0; k < F4PL; ++k) a[k] = w4[gl + 16 * k];
            float p = dot32(ek, a);
            #pragma unroll
            for (int m = 8; m >= 1; m >>= 1) p += __shfl_xor(p, m, 64);
            float s = p + bias[n];
            s = ((dirmask >> l) & 1ull) ? s : -s;
            lprod *= fast_sigmoid(s);
        }
    }

    // Combine 4 groups within the wave (multiplicative butterfly).
    lprod *= __shfl_xor(lprod, 16, 64);
    lprod *= __shfl_xor(lprod, 32, 64);

    // Combine 4 waves through LDS.
    if (lane == 0) wprod[wv] = lprod;
    __syncthreads();
    if (threadIdx.x == 0)
        out[b] = wprod[0] * wprod[1] * wprod[2] * wprod[3];
}

extern "C" void kernel_launch(void* const* d_in, const int* in_sizes, int n_in,
                              void* d_out, int out_size, void* d_ws, size_t ws_size,
                              hipStream_t stream)
{
    const float* emb    = (const float*)d_in[0];
    const float* W      = (const float*)d_in[1];
    const float* bias   = (const float*)d_in[2];
    const int*   target = (const int*)  d_in[3];
    const int*   nodes  = (const int*)  d_in[4];
    const int*   dirs   = (const int*)  d_in[5];
    float*       out    = (float*)d_out;

    const int B = in_sizes[3];              // 4096
    const int V = in_sizes[2] + 1;          // bias has V-1 entries
    const int L = in_sizes[4] / V;          // padded max path length (~27)

    hs_kernel<<<B, 256, 0, stream>>>(emb, W, bias, target, nodes, dirs, out, B, L);
}

// Round 2
// 163.204 us; speedup vs baseline: 1.0325x; 1.0325x over previous
//
#include <hip/hip_runtime.h>

// HierarchicalSoftmax: out[b] = prod_l sigmoid(+/- (W[node_l]·emb[b] + bias[node_l]))
//
// R3: software-pipelined gather. Model: kernel is gather-BW/duty-cycle bound
// (~200 MB of W rows; L3 flushed each iter by the harness re-poison fills).
// R1/R2 issued a load batch then fully drained it (dot + reduce chain) before
// the next -> ~50% memory duty cycle. R3 ping-pong double-buffers the W row
// per 16-lane group so a load batch is ALWAYS in flight:
//  - one wave per sample; group g owns levels {g, g+4, g+8, ...}
//  - explicit bufA/bufB (no copy, no register rotation needed)
//  - bias pre-gathered lane-parallel with path metadata (no in-loop gather)
//  - no LDS, no syncthreads; __launch_bounds__(256,4) pins VGPR<=128
//    (ek 32 + bufA 32 + bufB 32 + ~20 misc) -> 4 waves/SIMD.

#define HS_D 512
#define F4PL 8   // float4 per lane: 512 floats / 4 / 16 lanes

__device__ __forceinline__ float fast_sigmoid(float s) {
    // 1/(1+e^-s); v_rcp_f32 rel err ~1e-6, far under the 2%-of-max threshold
    return __builtin_amdgcn_rcpf(1.0f + __expf(-s));
}

__device__ __forceinline__ float dot32(const float4* __restrict__ e,
                                       const float4* __restrict__ a) {
    float p = e[0].x * a[0].x;
    #pragma unroll
    for (int k = 0; k < F4PL; ++k) {
        if (k) p = fmaf(e[k].x, a[k].x, p);
        p = fmaf(e[k].y, a[k].y, p);
        p = fmaf(e[k].z, a[k].z, p);
        p = fmaf(e[k].w, a[k].w, p);
    }
    return p;
}

__device__ __forceinline__ void loadrow(float4* __restrict__ dst,
                                        const float* __restrict__ W,
                                        int n, int gl) {
    const float4* w4 = (const float4*)(W + (size_t)n * HS_D);
    #pragma unroll
    for (int k = 0; k < F4PL; ++k) dst[k] = w4[gl + 16 * k];
}

__global__ __launch_bounds__(256, 4) void hs_kernel(
    const float* __restrict__ emb,     // [B, 512]
    const float* __restrict__ W,       // [V-1, 512]
    const float* __restrict__ bias,    // [V-1]
    const int*   __restrict__ target,  // [B]
    const int*   __restrict__ nodes,   // [V, L]
    const int*   __restrict__ dirs,    // [V, L]
    float*       __restrict__ out,     // [B]
    int B, int L)
{
    const int wid  = blockIdx.x * (blockDim.x >> 6) + (threadIdx.x >> 6);
    const int lane = threadIdx.x & 63;
    const int g    = lane >> 4;            // 16-lane group 0..3
    const int gl   = lane & 15;
    if (wid >= B) return;

    // Embedding chunk first (independent of the target->nodes dependency chain).
    const float4* e4 = (const float4*)(emb + (size_t)wid * HS_D);
    float4 ek[F4PL];
    #pragma unroll
    for (int k = 0; k < F4PL; ++k) ek[k] = e4[gl + 16 * k];

    const int t = __builtin_amdgcn_readfirstlane(target[wid]);

    // Lane-parallel preload of the whole path's metadata + bias (L ~ 27 < 64).
    int nval = 0, dval = 0;
    float bval = 0.0f;
    if (lane < L) {
        nval = nodes[(size_t)t * L + lane];
        dval = dirs [(size_t)t * L + lane];
        bval = bias[nval];                 // nval==0 padding -> bias[0], unused
    }
    // First node==0 along the row is the root (= last real step). 1-based pos.
    const unsigned long long rootmask = __ballot(lane < L && nval == 0);
    const int plen = __ffsll((long long)rootmask);
    const unsigned long long dirmask = __ballot(dval != 0);

    float lprod = 1.0f;
    float4 bufA[F4PL], bufB[F4PL];

    // Group g walks levels g, g+4, g+8, ... with 1-deep ping-pong prefetch.
    int l = g;
    if (l < plen) loadrow(bufA, W, __shfl(nval, l, 64), gl);

    while (l < plen) {
        // --- step on bufA (level l), prefetch into bufB (level l+4) ---
        {
            const int l2 = l + 4;
            if (l2 < plen) loadrow(bufB, W, __shfl(nval, l2 & 63, 64), gl);
            const float bi = __shfl(bval, l, 64);
            float p = dot32(ek, bufA);
            #pragma unroll
            for (int m = 8; m >= 1; m >>= 1) p += __shfl_xor(p, m, 64);
            float s = p + bi;
            s = ((dirmask >> l) & 1ull) ? s : -s;
            lprod *= fast_sigmoid(s);
            l = l2;
        }
        if (l >= plen) break;
        // --- step on bufB (level l), prefetch into bufA (level l+4) ---
        {
            const int l2 = l + 4;
            if (l2 < plen) loadrow(bufA, W, __shfl(nval, l2 & 63, 64), gl);
            const float bi = __shfl(bval, l, 64);
            float p = dot32(ek, bufB);
            #pragma unroll
            for (int m = 8; m >= 1; m >>= 1) p += __shfl_xor(p, m, 64);
            float s = p + bi;
            s = ((dirmask >> l) & 1ull) ? s : -s;
            lprod *= fast_sigmoid(s);
            l = l2;
        }
    }

    // Combine the 4 groups' partial products (multiplicative butterfly).
    lprod *= __shfl_xor(lprod, 16, 64);
    lprod *= __shfl_xor(lprod, 32, 64);

    if (lane == 0) out[wid] = lprod;
}

extern "C" void kernel_launch(void* const* d_in, const int* in_sizes, int n_in,
                              void* d_out, int out_size, void* d_ws, size_t ws_size,
                              hipStream_t stream)
{
    const float* emb    = (const float*)d_in[0];
    const float* W      = (const float*)d_in[1];
    const float* bias   = (const float*)d_in[2];
    const int*   target = (const int*)  d_in[3];
    const int*   nodes  = (const int*)  d_in[4];
    const int*   dirs   = (const int*)  d_in[5];
    float*       out    = (float*)d_out;

    const int B = in_sizes[3];              // 4096
    const int V = in_sizes[2] + 1;          // bias has V-1 entries
    const int L = in_sizes[4] / V;          // padded max path length (~27)

    const int wavesPerBlock = 4;            // 256 threads
    const int grid = (B + wavesPerBlock - 1) / wavesPerBlock;
    hs_kernel<<<grid, 256, 0, stream>>>(emb, W, bias, target, nodes, dirs, out, B, L);
}